// Round 22
// baseline (140.086 us; speedup 1.0000x reference)
//
#include <hip/hip_runtime.h>
#include <hip/hip_bf16.h>
#include <cstdint>

#define B_  4
#define T_  2048
#define C_  768
#define H_  12
#define HD_ 64

#define AS1 __attribute__((address_space(1)))
#define AS3 __attribute__((address_space(3)))

typedef float    f32x4  __attribute__((ext_vector_type(4)));
typedef __bf16   bf16x8 __attribute__((ext_vector_type(8)));
typedef uint32_t u32x4  __attribute__((ext_vector_type(4)));

// log2(e)/8: folded into Q at GEMM1 epilogue -> softmax runs in exp2 domain.
#define QSCL 0.18033688011112042f

__device__ __forceinline__ uint16_t f2b(float f) {   // native RNE cvt
  __bf16 h = (__bf16)f;
  return __builtin_bit_cast(uint16_t, h);
}
__device__ __forceinline__ uint32_t pk2(float a, float b) {
  return (uint32_t)f2b(a) | ((uint32_t)f2b(b) << 16);
}
__device__ __forceinline__ uint32_t cvtpk(float lo, float hi) {  // HW packed cvt
  uint32_t r;
  asm("v_cvt_pk_bf16_f32 %0, %1, %2" : "=v"(r) : "v"(lo), "v"(hi));
  return r;
}

// ---------------- fp32 -> bf16 cast (vectorized) ----------------
__global__ void k_cvt(const float* __restrict__ in, uint16_t* __restrict__ out, int n4) {
  int i = blockIdx.x * blockDim.x + threadIdx.x;
  if (i >= n4) return;
  float4 v = ((const float4*)in)[i];
  uint2 o;
  o.x = pk2(v.x, v.y);
  o.y = pk2(v.z, v.w);
  ((uint2*)out)[i] = o;
}

// ------- transpose + cast both weights: fp32 [R][Cc] -> bf16 [Cc][R] -------
__global__ void k_tr2(const float* __restrict__ Wa, uint16_t* __restrict__ WtA,
                      const float* __restrict__ Wp, uint16_t* __restrict__ WtP) {
  __shared__ float tile[32][33];
  const int bx = blockIdx.x;
  const float* in;
  uint16_t* out;
  int Cc, n0;
  if (bx < 72) { in = Wa; out = WtA; Cc = 2304; n0 = bx * 32; }
  else         { in = Wp; out = WtP; Cc = 768;  n0 = (bx - 72) * 32; }
  const int k0 = blockIdx.y * 32;
  const int tx = threadIdx.x, ty = threadIdx.y;  // (32,8)
#pragma unroll
  for (int i = 0; i < 32; i += 8)
    tile[ty + i][tx] = in[(size_t)(k0 + ty + i) * Cc + n0 + tx];
  __syncthreads();
#pragma unroll
  for (int i = 0; i < 32; i += 8)
    out[(size_t)(n0 + ty + i) * 768 + k0 + tx] = f2b(tile[tx][ty + i]);
}

// ------ GEMM1: 256x256 tile, BK=64, 8 waves (2Mx4N), dbuf 128KB, 1 blk/CU ------
// QKV = xb[8192,768] * WtA[2304,768]^T + b_attn, scattered per EPI-1 rules.
// Per K-tile group: [vmcnt(0) -> barrier -> STAGE(kt+1) -> 4 quadrants x
// (12 ds_read_b128 + 16 MFMA)]. Compute phase ~2500cy >> load latency, so
// dist-1 is safe here (r15 lesson: distance vs latency/phase ratio).
__global__ __launch_bounds__(512, 1) void k_gemm256(
    const uint16_t* __restrict__ A, const uint16_t* __restrict__ Bt,
    const float* __restrict__ bias, uint16_t* __restrict__ outQKV) {
  __shared__ __align__(16) uint16_t As[2][256 * 64];   // 64 KB
  __shared__ __align__(16) uint16_t Bs[2][256 * 64];   // 64 KB
  const int tid  = threadIdx.x;
  const int lane = tid & 63;
  const int wq   = tid >> 6;          // 0..7
  const int wm   = wq >> 2;           // 0..1  (M half)
  const int wn   = wq & 3;            // 0..3  (N quarter)
  const int l16  = lane & 15, kg = lane >> 4;

  const int bid  = blockIdx.x;        // 288 blocks, 288%8==0 -> bijective swizzle
  const int wgid = (bid & 7) * 36 + (bid >> 3);
  const int wx = wgid / 9, wy = wgid % 9;
  const int rowBase = wx * 256, colBase = wy * 256;

  f32x4 acc[8][4];
#pragma unroll
  for (int i = 0; i < 8; ++i)
#pragma unroll
    for (int j = 0; j < 4; ++j) acc[i][j] = (f32x4){0.f, 0.f, 0.f, 0.f};

  const int srow  = tid >> 3;         // 0..63 (wave w covers rows w*8..w*8+7)
  const int sslot = tid & 7;
  const int ssw   = ((sslot ^ (srow & 7)) << 3);

  auto STAGE = [&](int buf, int kt) {  // 8 global_load_lds per thread
    const int k0 = kt * 64;
#pragma unroll
    for (int j = 0; j < 4; ++j) {
      const uint16_t* srcA = A + (size_t)(rowBase + j * 64 + srow) * 768 + k0 + ssw;
      __builtin_amdgcn_global_load_lds((const AS1 uint32_t*)srcA,
          (AS3 uint32_t*)&As[buf][(j * 64 + wq * 8) * 64], 16, 0, 0);
    }
#pragma unroll
    for (int j = 0; j < 4; ++j) {
      const uint16_t* srcB = Bt + (size_t)(colBase + j * 64 + srow) * 768 + k0 + ssw;
      __builtin_amdgcn_global_load_lds((const AS1 uint32_t*)srcB,
          (AS3 uint32_t*)&Bs[buf][(j * 64 + wq * 8) * 64], 16, 0, 0);
    }
  };

  STAGE(0, 0);
  for (int kt = 0; kt < 12; ++kt) {
    const int g = kt & 1;
    asm volatile("s_waitcnt vmcnt(0)" ::: "memory");  // buf g staged
    __builtin_amdgcn_sched_barrier(0);
    __builtin_amdgcn_s_barrier();       // all waves: g ready, prior g^1 reads done

    if (kt + 1 < 12) STAGE(g ^ 1, kt + 1);

    const uint16_t* AT = &As[g][0];
    const uint16_t* BT = &Bs[g][0];
#pragma unroll
    for (int qm = 0; qm < 2; ++qm)
#pragma unroll
      for (int qn = 0; qn < 2; ++qn) {
        bf16x8 af[4][2], bfv[2][2];
#pragma unroll
        for (int mi = 0; mi < 4; ++mi) {
          const int row = wm * 128 + qm * 64 + mi * 16 + l16;
#pragma unroll
          for (int kc = 0; kc < 2; ++kc)
            af[mi][kc] = *(const bf16x8*)&AT[row * 64 + (((kc * 4 + kg) ^ (row & 7)) << 3)];
        }
#pragma unroll
        for (int nj = 0; nj < 2; ++nj) {
          const int row = wn * 64 + qn * 32 + nj * 16 + l16;
#pragma unroll
          for (int kc = 0; kc < 2; ++kc)
            bfv[nj][kc] = *(const bf16x8*)&BT[row * 64 + (((kc * 4 + kg) ^ (row & 7)) << 3)];
        }
        __builtin_amdgcn_s_setprio(1);
#pragma unroll
        for (int mi = 0; mi < 4; ++mi)
#pragma unroll
          for (int nj = 0; nj < 2; ++nj)
#pragma unroll
            for (int kc = 0; kc < 2; ++kc)
              acc[qm * 4 + mi][qn * 2 + nj] = __builtin_amdgcn_mfma_f32_16x16x32_bf16(
                  af[mi][kc], bfv[nj][kc], acc[qm * 4 + mi][qn * 2 + nj], 0, 0, 0);
        __builtin_amdgcn_s_setprio(0);
      }
  }

  // epilogue: QKV scatter (EPI-1 semantics)
#pragma unroll
  for (int mi = 0; mi < 8; ++mi)
#pragma unroll
    for (int nj = 0; nj < 4; ++nj) {
      int c = colBase + wn * 64 + nj * 16 + l16;
      float bv = bias[c];
      int sel = c / 768;
      int rem = c - sel * 768;
      int head = rem >> 6, d = rem & 63;
      int r0 = rowBase + wm * 128 + mi * 16 + kg * 4;
      int bb = r0 >> 11, tt0 = r0 & 2047;
      if (sel == 2) {   // V^T [B,H,64,T]: 4 consecutive tt -> one 8B store
        size_t off = (((size_t)2 * (B_ * H_) + bb * H_ + head) * HD_ + d) * T_ + tt0;
        uint2 w;
        w.x = pk2(acc[mi][nj][0] + bv, acc[mi][nj][1] + bv);
        w.y = pk2(acc[mi][nj][2] + bv, acc[mi][nj][3] + bv);
        *(uint2*)&outQKV[off] = w;
      } else {
        float scl = (sel == 0) ? QSCL : 1.0f;
#pragma unroll
        for (int jj = 0; jj < 4; ++jj) {
          size_t off = (((size_t)sel * (B_ * H_) + bb * H_ + head) * T_ + tt0 + jj) * HD_ + d;
          outQKV[off] = f2b((acc[mi][nj][jj] + bv) * scl);
        }
      }
    }
}

// ---------------- MFMA bf16 GEMM (r13 exact — used for GEMM2) ----------------
template <int EPI>
__global__ __launch_bounds__(256, 3) void k_gemm(
    const uint16_t* __restrict__ A, const uint16_t* __restrict__ Bt,
    const float* __restrict__ bias, float* __restrict__ outF,
    uint16_t* __restrict__ outQKV, int M, int N, int K, int nY) {
  __shared__ __align__(16) uint16_t As[3][128 * 32];
  __shared__ __align__(16) uint16_t Bs[3][128 * 32];
  const int nwg = gridDim.x;
  const int bid = blockIdx.x;
  const int wgid = (bid & 7) * (nwg >> 3) + (bid >> 3);
  const int wy = wgid % nY, wx = wgid / nY;

  const int tid  = threadIdx.x;
  const int lane = tid & 63;
  const int wave = tid >> 6;
  const int wrow = (wave >> 1) * 64, wcol = (wave & 1) * 64;
  const int rowBase = wx * 128, colBase = wy * 128;
  const int l16 = lane & 15, kg = lane >> 4;

  f32x4 acc[4][4];
#pragma unroll
  for (int i = 0; i < 4; ++i)
#pragma unroll
    for (int j = 0; j < 4; ++j) acc[i][j] = (f32x4){0.f, 0.f, 0.f, 0.f};

  const int srow  = lane >> 2;
  const int sslot = lane & 3;
  const int ssw   = (sslot ^ (srow & 3)) << 3;

  auto STAGE = [&](int buf, int k0) {
#pragma unroll
    for (int i = 0; i < 2; ++i) {
      const int r = i * 64 + wave * 16 + srow;
      const uint16_t* srcA = A  + (size_t)(rowBase + r) * K + k0 + ssw;
      const uint16_t* srcB = Bt + (size_t)(colBase + r) * K + k0 + ssw;
      uint16_t* dstA = &As[buf][(i * 64 + wave * 16) * 32];
      uint16_t* dstB = &Bs[buf][(i * 64 + wave * 16) * 32];
      __builtin_amdgcn_global_load_lds((const AS1 uint32_t*)srcA, (AS3 uint32_t*)dstA, 16, 0, 0);
      __builtin_amdgcn_global_load_lds((const AS1 uint32_t*)srcB, (AS3 uint32_t*)dstB, 16, 0, 0);
    }
  };

  const int sA = (kg ^ (l16 & 3)) << 3;

  STAGE(0, 0);
  if (32 < K) STAGE(1, 32);
  int t = 0;
  for (int k0 = 0; k0 < K; k0 += 32, ++t) {
    if (k0 + 32 < K) {
      asm volatile("s_waitcnt vmcnt(4)" ::: "memory");
    } else {
      asm volatile("s_waitcnt vmcnt(0)" ::: "memory");
    }
    __builtin_amdgcn_sched_barrier(0);
    __builtin_amdgcn_s_barrier();

    if (k0 + 64 < K) STAGE((t + 2) % 3, k0 + 64);

    const int cb = t % 3;
    bf16x8 af[4], bfv[4];
#pragma unroll
    for (int mi = 0; mi < 4; ++mi)
      af[mi] = *(const bf16x8*)&As[cb][(wrow + mi * 16 + l16) * 32 + sA];
#pragma unroll
    for (int nj = 0; nj < 4; ++nj)
      bfv[nj] = *(const bf16x8*)&Bs[cb][(wcol + nj * 16 + l16) * 32 + sA];
#pragma unroll
    for (int mi = 0; mi < 4; ++mi)
#pragma unroll
      for (int nj = 0; nj < 4; ++nj)
        acc[mi][nj] = __builtin_amdgcn_mfma_f32_16x16x32_bf16(af[mi], bfv[nj], acc[mi][nj], 0, 0, 0);
  }

  const int rg = lane >> 4;
#pragma unroll
  for (int mi = 0; mi < 4; ++mi)
#pragma unroll
    for (int nj = 0; nj < 4; ++nj) {
      int c = colBase + wcol + nj * 16 + l16;
      float bv = bias[c];
      if (EPI == 0) {
#pragma unroll
        for (int jj = 0; jj < 4; ++jj) {
          int r = rowBase + wrow + mi * 16 + rg * 4 + jj;
          outF[(size_t)r * N + c] = acc[mi][nj][jj] + bv;
        }
      } else {
        int sel = c / 768;
        int rem = c - sel * 768;
        int head = rem >> 6, d = rem & 63;
        int r0 = rowBase + wrow + mi * 16 + rg * 4;
        int bb = r0 >> 11, tt0 = r0 & 2047;
        if (sel == 2) {
          size_t off = (((size_t)2 * (B_ * H_) + bb * H_ + head) * HD_ + d) * T_ + tt0;
          uint2 w;
          w.x = pk2(acc[mi][nj][0] + bv, acc[mi][nj][1] + bv);
          w.y = pk2(acc[mi][nj][2] + bv, acc[mi][nj][3] + bv);
          *(uint2*)&outQKV[off] = w;
        } else {
          float scl = (sel == 0) ? QSCL : 1.0f;
#pragma unroll
          for (int jj = 0; jj < 4; ++jj) {
            size_t off = (((size_t)sel * (B_ * H_) + bb * H_ + head) * T_ + tt0 + jj) * HD_ + d;
            outQKV[off] = f2b((acc[mi][nj][jj] + bv) * scl);
          }
        }
      }
    }
}

// ---------------- MFMA flash attention, v11b (r19 exact — best measured) ----------------
__global__ __launch_bounds__(512, 6) void k_attn2(
    const uint16_t* __restrict__ Qb, const uint16_t* __restrict__ Kb,
    const uint16_t* __restrict__ Vb, uint16_t* __restrict__ Y) {
  __shared__ __align__(16) uint16_t Ks[2][64 * 64];
  __shared__ __align__(16) uint16_t Vs[2][64 * 64];
  __shared__ __align__(16) uint32_t Pw[8][16 * 20];   // per-wave P: 16 q x 32 kv
  const int tid  = threadIdx.x;
  const int lane = tid & 63;
  const int wq   = tid >> 6;           // wave 0..7
  const int qw   = wq & 3;             // q sub-block
  const int kh   = wq >> 2;            // kv half
  const int l16  = lane & 15, kg = lane >> 4;

  const int idx = blockIdx.x;
  const int tq  = idx >> 3;
  const int px  = tq & 15;
  const int g   = (idx & 7) + 8 * (tq >> 4);
  const int h = g % H_, b = g / H_;
  const size_t headBase = ((size_t)(b * H_ + h)) * (size_t)(T_ * HD_);

  const int srow0 = tid >> 3;          // 0..63
  const int sslot = lane & 7;
  const int ssw   = ((sslot ^ (srow0 & 7)) << 3);

  uint32_t* pw = &Pw[wq][0];
  uint16_t* dstK0 = &Ks[0][(wq * 8) * 64];
  uint16_t* dstK1 = &Ks[1][(wq * 8) * 64];
  uint16_t* dstV0 = &Vs[0][(wq * 8) * 64];
  uint16_t* dstV1 = &Vs[1][(wq * 8) * 64];

  // constant ones A-fragment for the l-summing MFMA
  u32x4 onesw;
  onesw[0] = 0x3f803f80u; onesw[1] = 0x3f803f80u;
  onesw[2] = 0x3f803f80u; onesw[3] = 0x3f803f80u;
  const bf16x8 onesf = __builtin_bit_cast(bf16x8, onesw);

  int cur = 0;
  for (int part = 0; part < 2; ++part) {
    const int qb = part ? (31 - px) : px;
    const int qrow0 = qb * 64 + qw * 16;

    bf16x8 qf[2];
    {
      const uint16_t* qp = Qb + headBase + (size_t)(qrow0 + l16) * HD_;
      qf[0] = *(const bf16x8*)(qp + kg * 8);
      qf[1] = *(const bf16x8*)(qp + 32 + kg * 8);
    }

    f32x4 o[4];
#pragma unroll
    for (int i = 0; i < 4; ++i) o[i] = (f32x4){0.f, 0.f, 0.f, 0.f};
    f32x4 lq = (f32x4){0.f, 0.f, 0.f, 0.f};   // l accumulator (ones-MFMA)

    // strength-reduced staging pointers (advance per STAGE call)
    const uint16_t* kp = Kb + headBase + (size_t)srow0 * HD_ + ssw;
    const uint16_t* vp = Vb + headBase + (size_t)srow0 * T_ + ssw;

    auto STAGE = [&](int buf) {          // 2 global_load_lds per thread
      __builtin_amdgcn_global_load_lds((const AS1 uint32_t*)kp,
                                       (AS3 uint32_t*)(buf ? dstK1 : dstK0), 16, 0, 0);
      __builtin_amdgcn_global_load_lds((const AS1 uint32_t*)vp,
                                       (AS3 uint32_t*)(buf ? dstV1 : dstV0), 16, 0, 0);
      kp += 64 * HD_;                    // next kv tile: +64 rows
      vp += 64;                          // next kv tile: +64 cols
    };

    const int nt = qb + 1;
    __syncthreads();          // part boundary: prior combine reads done
    STAGE(cur);

    for (int t = 0; t < nt; ++t) {
      asm volatile("s_waitcnt vmcnt(0)" ::: "memory");  // tile t landed (issued 1 phase ago)
      __builtin_amdgcn_sched_barrier(0);
      __builtin_amdgcn_s_barrier();      // all waves: t ready, compute(t-1) done

      if (t + 1 < nt) STAGE(cur ^ 1);    // overwrite safe: everyone passed barrier

      const uint16_t* KT = &Ks[cur][0];
      const uint16_t* VT = &Vs[cur][0];

      // --- S^T half: sm[nj][jj] = S[kv = kh*32+nj*16+kg*4+jj][q = l16] ---
      f32x4 sm[2];
      __builtin_amdgcn_s_setprio(1);
#pragma unroll
      for (int nj = 0; nj < 2; ++nj) {
        f32x4 acc = (f32x4){0.f, 0.f, 0.f, 0.f};
        const int row = kh * 32 + nj * 16 + l16;
#pragma unroll
        for (int kc = 0; kc < 2; ++kc) {
          const int s = (((kc * 4 + kg) ^ (row & 7)) << 3);
          bf16x8 kf = *(const bf16x8*)&KT[row * 64 + s];
          acc = __builtin_amdgcn_mfma_f32_16x16x32_bf16(kf, qf[kc], acc, 0, 0, 0);
        }
        sm[nj] = acc;
      }
      __builtin_amdgcn_s_setprio(0);

      if (t == qb) {  // diagonal tile: causal mask
        const int kvb = t * 64 + kh * 32 + kg * 4;
        const int qg  = qrow0 + l16;
#pragma unroll
        for (int nj = 0; nj < 2; ++nj)
#pragma unroll
          for (int jj = 0; jj < 4; ++jj)
            if (kvb + nj * 16 + jj > qg) sm[nj][jj] = -__builtin_inff();
      }

      // --- softmax numerator: p = exp2(S) (scale cancels in O/l) ---
#pragma unroll
      for (int nj = 0; nj < 2; ++nj)
#pragma unroll
        for (int jj = 0; jj < 4; ++jj)
          sm[nj][jj] = __builtin_exp2f(sm[nj][jj]);

      // --- P -> private LDS (row q=l16, 32 kv, stride 20 words); HW cvt_pk ---
#pragma unroll
      for (int nj = 0; nj < 2; ++nj) {
        uint2 w;
        w.x = cvtpk(sm[nj][0], sm[nj][1]);
        w.y = cvtpk(sm[nj][2], sm[nj][3]);
        *(uint2*)&pw[l16 * 20 + nj * 8 + kg * 2] = w;
      }

      // --- O^T(partial) += V^T[:, my half] P ; l via ones-MFMA ---
      __builtin_amdgcn_s_setprio(1);
      bf16x8 pa = *(const bf16x8*)&pw[l16 * 20 + kg * 4];
#pragma unroll
      for (int njd = 0; njd < 4; ++njd) {
        const int row = njd * 16 + l16;
        const int s = (((kh * 4 + kg) ^ (row & 7)) << 3);
        bf16x8 vf = *(const bf16x8*)&VT[row * 64 + s];
        o[njd] = __builtin_amdgcn_mfma_f32_16x16x32_bf16(vf, pa, o[njd], 0, 0, 0);
      }
      lq = __builtin_amdgcn_mfma_f32_16x16x32_bf16(onesf, pa, lq, 0, 0, 0);
      __builtin_amdgcn_s_setprio(0);

      cur ^= 1;
    }

    // --- combine kv-half partials via freed K/V LDS, then store ---
    float l_ = lq[0];                    // every lane holds l(q=l16) already

    __syncthreads();                     // all visits' LDS reads done
    f32x4* cO = (f32x4*)&Ks[0][0];
    float*  cL = (float*)&Vs[0][0];
    if (kh) {
#pragma unroll
      for (int njd = 0; njd < 4; ++njd) cO[(njd * 4 + qw) * 64 + lane] = o[njd];
      if (lane < 16) cL[qw * 64 + lane] = l_;
    }
    __syncthreads();
    if (!kh) {
      float lsum = l_ + cL[qw * 64 + l16];
      float inv = __builtin_amdgcn_rcpf(lsum);
      const int q = qrow0 + l16;
      uint16_t* yp = Y + ((size_t)(b * T_ + q)) * C_ + h * HD_ + kg * 4;
#pragma unroll
      for (int njd = 0; njd < 4; ++njd) {
        f32x4 oc = o[njd] + cO[(njd * 4 + qw) * 64 + lane];
        uint2 w;
        w.x = cvtpk(oc[0] * inv, oc[1] * inv);
        w.y = cvtpk(oc[2] * inv, oc[3] * inv);
        *(uint2*)(yp + njd * 16) = w;
      }
    }
  }
}

extern "C" void kernel_launch(void* const* d_in, const int* in_sizes, int n_in,
                              void* d_out, int out_size, void* d_ws, size_t ws_size,
                              hipStream_t stream) {
  const float* x      = (const float*)d_in[0];
  const float* W_attn = (const float*)d_in[1];
  const float* b_attn = (const float*)d_in[2];
  const float* W_proj = (const float*)d_in[3];
  const float* b_proj = (const float*)d_in[4];
  float* out = (float*)d_out;

  char* ws = (char*)d_ws;
  uint16_t* xb  = (uint16_t*)(ws);
  uint16_t* WtA = (uint16_t*)(ws + 12582912);
  uint16_t* WtP = (uint16_t*)(ws + 16121856);
  uint16_t* QKV = (uint16_t*)(ws + 17301504);
  uint16_t* Yb  = (uint16_t*)(ws + 55050240);

  uint16_t* Qp = QKV;                // pre-scaled by QSCL
  uint16_t* Kp = QKV + 6291456;
  uint16_t* Vp = QKV + 12582912;     // [B,H,64,T]

  k_cvt<<<6144, 256, 0, stream>>>(x, xb, 1572864);
  k_tr2<<<dim3(96, 24), dim3(32, 8), 0, stream>>>(W_attn, WtA, W_proj, WtP);
  k_gemm256<<<288, 512, 0, stream>>>(xb, WtA, b_attn, QKV);
  k_attn2<<<768, 512, 0, stream>>>(Qp, Kp, Vp, Yb);
  k_gemm<0><<<384, 256, 0, stream>>>(Yb, WtP, b_proj, out, nullptr, 8192, 768, 768, 6);
}

// Round 23
// 130.378 us; speedup vs baseline: 1.0745x; 1.0745x over previous
//
#include <hip/hip_runtime.h>
#include <hip/hip_bf16.h>
#include <cstdint>

#define B_  4
#define T_  2048
#define C_  768
#define H_  12
#define HD_ 64

#define AS1 __attribute__((address_space(1)))
#define AS3 __attribute__((address_space(3)))

typedef float    f32x4  __attribute__((ext_vector_type(4)));
typedef __bf16   bf16x8 __attribute__((ext_vector_type(8)));
typedef uint32_t u32x4  __attribute__((ext_vector_type(4)));

// log2(e)/8: folded into Q at GEMM1 epilogue -> softmax runs in exp2 domain.
#define QSCL 0.18033688011112042f

__device__ __forceinline__ uint16_t f2b(float f) {   // native RNE cvt
  __bf16 h = (__bf16)f;
  return __builtin_bit_cast(uint16_t, h);
}
__device__ __forceinline__ uint32_t pk2(float a, float b) {
  return (uint32_t)f2b(a) | ((uint32_t)f2b(b) << 16);
}
__device__ __forceinline__ uint32_t cvtpk(float lo, float hi) {  // HW packed cvt
  uint32_t r;
  asm("v_cvt_pk_bf16_f32 %0, %1, %2" : "=v"(r) : "v"(lo), "v"(hi));
  return r;
}

// ---------------- fp32 -> bf16 cast (vectorized) ----------------
__global__ void k_cvt(const float* __restrict__ in, uint16_t* __restrict__ out, int n4) {
  int i = blockIdx.x * blockDim.x + threadIdx.x;
  if (i >= n4) return;
  float4 v = ((const float4*)in)[i];
  uint2 o;
  o.x = pk2(v.x, v.y);
  o.y = pk2(v.z, v.w);
  ((uint2*)out)[i] = o;
}

// ------- transpose + cast both weights: fp32 [R][Cc] -> bf16 [Cc][R] -------
__global__ void k_tr2(const float* __restrict__ Wa, uint16_t* __restrict__ WtA,
                      const float* __restrict__ Wp, uint16_t* __restrict__ WtP) {
  __shared__ float tile[32][33];
  const int bx = blockIdx.x;
  const float* in;
  uint16_t* out;
  int Cc, n0;
  if (bx < 72) { in = Wa; out = WtA; Cc = 2304; n0 = bx * 32; }
  else         { in = Wp; out = WtP; Cc = 768;  n0 = (bx - 72) * 32; }
  const int k0 = blockIdx.y * 32;
  const int tx = threadIdx.x, ty = threadIdx.y;  // (32,8)
#pragma unroll
  for (int i = 0; i < 32; i += 8)
    tile[ty + i][tx] = in[(size_t)(k0 + ty + i) * Cc + n0 + tx];
  __syncthreads();
#pragma unroll
  for (int i = 0; i < 32; i += 8)
    out[(size_t)(n0 + ty + i) * 768 + k0 + tx] = f2b(tile[tx][ty + i]);
}

// ---------------- MFMA bf16 GEMM (r13 exact — 55 us measured; dist-2,
// 3 buffers, vmcnt(4) steady-state; 1 barrier per k-step) ----------------
template <int EPI>
__global__ __launch_bounds__(256, 3) void k_gemm(
    const uint16_t* __restrict__ A, const uint16_t* __restrict__ Bt,
    const float* __restrict__ bias, float* __restrict__ outF,
    uint16_t* __restrict__ outQKV, int M, int N, int K, int nY) {
  __shared__ __align__(16) uint16_t As[3][128 * 32];
  __shared__ __align__(16) uint16_t Bs[3][128 * 32];
  const int nwg = gridDim.x;
  const int bid = blockIdx.x;
  const int wgid = (bid & 7) * (nwg >> 3) + (bid >> 3);
  const int wy = wgid % nY, wx = wgid / nY;

  const int tid  = threadIdx.x;
  const int lane = tid & 63;
  const int wave = tid >> 6;
  const int wrow = (wave >> 1) * 64, wcol = (wave & 1) * 64;
  const int rowBase = wx * 128, colBase = wy * 128;
  const int l16 = lane & 15, kg = lane >> 4;

  f32x4 acc[4][4];
#pragma unroll
  for (int i = 0; i < 4; ++i)
#pragma unroll
    for (int j = 0; j < 4; ++j) acc[i][j] = (f32x4){0.f, 0.f, 0.f, 0.f};

  const int srow  = lane >> 2;
  const int sslot = lane & 3;
  const int ssw   = (sslot ^ (srow & 3)) << 3;

  auto STAGE = [&](int buf, int k0) {
#pragma unroll
    for (int i = 0; i < 2; ++i) {
      const int r = i * 64 + wave * 16 + srow;
      const uint16_t* srcA = A  + (size_t)(rowBase + r) * K + k0 + ssw;
      const uint16_t* srcB = Bt + (size_t)(colBase + r) * K + k0 + ssw;
      uint16_t* dstA = &As[buf][(i * 64 + wave * 16) * 32];
      uint16_t* dstB = &Bs[buf][(i * 64 + wave * 16) * 32];
      __builtin_amdgcn_global_load_lds((const AS1 uint32_t*)srcA, (AS3 uint32_t*)dstA, 16, 0, 0);
      __builtin_amdgcn_global_load_lds((const AS1 uint32_t*)srcB, (AS3 uint32_t*)dstB, 16, 0, 0);
    }
  };

  const int sA = (kg ^ (l16 & 3)) << 3;

  STAGE(0, 0);
  if (32 < K) STAGE(1, 32);
  int t = 0;
  for (int k0 = 0; k0 < K; k0 += 32, ++t) {
    if (k0 + 32 < K) {
      asm volatile("s_waitcnt vmcnt(4)" ::: "memory");
    } else {
      asm volatile("s_waitcnt vmcnt(0)" ::: "memory");
    }
    __builtin_amdgcn_sched_barrier(0);
    __builtin_amdgcn_s_barrier();

    if (k0 + 64 < K) STAGE((t + 2) % 3, k0 + 64);

    const int cb = t % 3;
    bf16x8 af[4], bfv[4];
#pragma unroll
    for (int mi = 0; mi < 4; ++mi)
      af[mi] = *(const bf16x8*)&As[cb][(wrow + mi * 16 + l16) * 32 + sA];
#pragma unroll
    for (int nj = 0; nj < 4; ++nj)
      bfv[nj] = *(const bf16x8*)&Bs[cb][(wcol + nj * 16 + l16) * 32 + sA];
#pragma unroll
    for (int mi = 0; mi < 4; ++mi)
#pragma unroll
      for (int nj = 0; nj < 4; ++nj)
        acc[mi][nj] = __builtin_amdgcn_mfma_f32_16x16x32_bf16(af[mi], bfv[nj], acc[mi][nj], 0, 0, 0);
  }

  const int rg = lane >> 4;
#pragma unroll
  for (int mi = 0; mi < 4; ++mi)
#pragma unroll
    for (int nj = 0; nj < 4; ++nj) {
      int c = colBase + wcol + nj * 16 + l16;
      float bv = bias[c];
      if (EPI == 0) {
#pragma unroll
        for (int jj = 0; jj < 4; ++jj) {
          int r = rowBase + wrow + mi * 16 + rg * 4 + jj;
          outF[(size_t)r * N + c] = acc[mi][nj][jj] + bv;
        }
      } else {
        int sel = c / 768;
        int rem = c - sel * 768;
        int head = rem >> 6, d = rem & 63;
        int r0 = rowBase + wrow + mi * 16 + rg * 4;
        int bb = r0 >> 11, tt0 = r0 & 2047;
        if (sel == 2) {
          size_t off = (((size_t)2 * (B_ * H_) + bb * H_ + head) * HD_ + d) * T_ + tt0;
          uint2 w;
          w.x = pk2(acc[mi][nj][0] + bv, acc[mi][nj][1] + bv);
          w.y = pk2(acc[mi][nj][2] + bv, acc[mi][nj][3] + bv);
          *(uint2*)&outQKV[off] = w;
        } else {
          float scl = (sel == 0) ? QSCL : 1.0f;
#pragma unroll
          for (int jj = 0; jj < 4; ++jj) {
            size_t off = (((size_t)sel * (B_ * H_) + bb * H_ + head) * T_ + tt0 + jj) * HD_ + d;
            outQKV[off] = f2b((acc[mi][nj][jj] + bv) * scl);
          }
        }
      }
    }
}

// ---------------- MFMA flash attention, v11b (r19 exact — best measured) ----------------
__global__ __launch_bounds__(512, 6) void k_attn2(
    const uint16_t* __restrict__ Qb, const uint16_t* __restrict__ Kb,
    const uint16_t* __restrict__ Vb, uint16_t* __restrict__ Y) {
  __shared__ __align__(16) uint16_t Ks[2][64 * 64];
  __shared__ __align__(16) uint16_t Vs[2][64 * 64];
  __shared__ __align__(16) uint32_t Pw[8][16 * 20];   // per-wave P: 16 q x 32 kv
  const int tid  = threadIdx.x;
  const int lane = tid & 63;
  const int wq   = tid >> 6;           // wave 0..7
  const int qw   = wq & 3;             // q sub-block
  const int kh   = wq >> 2;            // kv half
  const int l16  = lane & 15, kg = lane >> 4;

  const int idx = blockIdx.x;
  const int tq  = idx >> 3;
  const int px  = tq & 15;
  const int g   = (idx & 7) + 8 * (tq >> 4);
  const int h = g % H_, b = g / H_;
  const size_t headBase = ((size_t)(b * H_ + h)) * (size_t)(T_ * HD_);

  const int srow0 = tid >> 3;          // 0..63
  const int sslot = lane & 7;
  const int ssw   = ((sslot ^ (srow0 & 7)) << 3);

  uint32_t* pw = &Pw[wq][0];
  uint16_t* dstK0 = &Ks[0][(wq * 8) * 64];
  uint16_t* dstK1 = &Ks[1][(wq * 8) * 64];
  uint16_t* dstV0 = &Vs[0][(wq * 8) * 64];
  uint16_t* dstV1 = &Vs[1][(wq * 8) * 64];

  // constant ones A-fragment for the l-summing MFMA
  u32x4 onesw;
  onesw[0] = 0x3f803f80u; onesw[1] = 0x3f803f80u;
  onesw[2] = 0x3f803f80u; onesw[3] = 0x3f803f80u;
  const bf16x8 onesf = __builtin_bit_cast(bf16x8, onesw);

  int cur = 0;
  for (int part = 0; part < 2; ++part) {
    const int qb = part ? (31 - px) : px;
    const int qrow0 = qb * 64 + qw * 16;

    bf16x8 qf[2];
    {
      const uint16_t* qp = Qb + headBase + (size_t)(qrow0 + l16) * HD_;
      qf[0] = *(const bf16x8*)(qp + kg * 8);
      qf[1] = *(const bf16x8*)(qp + 32 + kg * 8);
    }

    f32x4 o[4];
#pragma unroll
    for (int i = 0; i < 4; ++i) o[i] = (f32x4){0.f, 0.f, 0.f, 0.f};
    f32x4 lq = (f32x4){0.f, 0.f, 0.f, 0.f};   // l accumulator (ones-MFMA)

    // strength-reduced staging pointers (advance per STAGE call)
    const uint16_t* kp = Kb + headBase + (size_t)srow0 * HD_ + ssw;
    const uint16_t* vp = Vb + headBase + (size_t)srow0 * T_ + ssw;

    auto STAGE = [&](int buf) {          // 2 global_load_lds per thread
      __builtin_amdgcn_global_load_lds((const AS1 uint32_t*)kp,
                                       (AS3 uint32_t*)(buf ? dstK1 : dstK0), 16, 0, 0);
      __builtin_amdgcn_global_load_lds((const AS1 uint32_t*)vp,
                                       (AS3 uint32_t*)(buf ? dstV1 : dstV0), 16, 0, 0);
      kp += 64 * HD_;                    // next kv tile: +64 rows
      vp += 64;                          // next kv tile: +64 cols
    };

    const int nt = qb + 1;
    __syncthreads();          // part boundary: prior combine reads done
    STAGE(cur);

    for (int t = 0; t < nt; ++t) {
      asm volatile("s_waitcnt vmcnt(0)" ::: "memory");  // tile t landed (issued 1 phase ago)
      __builtin_amdgcn_sched_barrier(0);
      __builtin_amdgcn_s_barrier();      // all waves: t ready, compute(t-1) done

      if (t + 1 < nt) STAGE(cur ^ 1);    // overwrite safe: everyone passed barrier

      const uint16_t* KT = &Ks[cur][0];
      const uint16_t* VT = &Vs[cur][0];

      // --- S^T half: sm[nj][jj] = S[kv = kh*32+nj*16+kg*4+jj][q = l16] ---
      f32x4 sm[2];
      __builtin_amdgcn_s_setprio(1);
#pragma unroll
      for (int nj = 0; nj < 2; ++nj) {
        f32x4 acc = (f32x4){0.f, 0.f, 0.f, 0.f};
        const int row = kh * 32 + nj * 16 + l16;
#pragma unroll
        for (int kc = 0; kc < 2; ++kc) {
          const int s = (((kc * 4 + kg) ^ (row & 7)) << 3);
          bf16x8 kf = *(const bf16x8*)&KT[row * 64 + s];
          acc = __builtin_amdgcn_mfma_f32_16x16x32_bf16(kf, qf[kc], acc, 0, 0, 0);
        }
        sm[nj] = acc;
      }
      __builtin_amdgcn_s_setprio(0);

      if (t == qb) {  // diagonal tile: causal mask
        const int kvb = t * 64 + kh * 32 + kg * 4;
        const int qg  = qrow0 + l16;
#pragma unroll
        for (int nj = 0; nj < 2; ++nj)
#pragma unroll
          for (int jj = 0; jj < 4; ++jj)
            if (kvb + nj * 16 + jj > qg) sm[nj][jj] = -__builtin_inff();
      }

      // --- softmax numerator: p = exp2(S) (scale cancels in O/l) ---
#pragma unroll
      for (int nj = 0; nj < 2; ++nj)
#pragma unroll
        for (int jj = 0; jj < 4; ++jj)
          sm[nj][jj] = __builtin_exp2f(sm[nj][jj]);

      // --- P -> private LDS (row q=l16, 32 kv, stride 20 words); HW cvt_pk ---
#pragma unroll
      for (int nj = 0; nj < 2; ++nj) {
        uint2 w;
        w.x = cvtpk(sm[nj][0], sm[nj][1]);
        w.y = cvtpk(sm[nj][2], sm[nj][3]);
        *(uint2*)&pw[l16 * 20 + nj * 8 + kg * 2] = w;
      }

      // --- O^T(partial) += V^T[:, my half] P ; l via ones-MFMA ---
      __builtin_amdgcn_s_setprio(1);
      bf16x8 pa = *(const bf16x8*)&pw[l16 * 20 + kg * 4];
#pragma unroll
      for (int njd = 0; njd < 4; ++njd) {
        const int row = njd * 16 + l16;
        const int s = (((kh * 4 + kg) ^ (row & 7)) << 3);
        bf16x8 vf = *(const bf16x8*)&VT[row * 64 + s];
        o[njd] = __builtin_amdgcn_mfma_f32_16x16x32_bf16(vf, pa, o[njd], 0, 0, 0);
      }
      lq = __builtin_amdgcn_mfma_f32_16x16x32_bf16(onesf, pa, lq, 0, 0, 0);
      __builtin_amdgcn_s_setprio(0);

      cur ^= 1;
    }

    // --- combine kv-half partials via freed K/V LDS, then store ---
    float l_ = lq[0];                    // every lane holds l(q=l16) already

    __syncthreads();                     // all visits' LDS reads done
    f32x4* cO = (f32x4*)&Ks[0][0];
    float*  cL = (float*)&Vs[0][0];
    if (kh) {
#pragma unroll
      for (int njd = 0; njd < 4; ++njd) cO[(njd * 4 + qw) * 64 + lane] = o[njd];
      if (lane < 16) cL[qw * 64 + lane] = l_;
    }
    __syncthreads();
    if (!kh) {
      float lsum = l_ + cL[qw * 64 + l16];
      float inv = __builtin_amdgcn_rcpf(lsum);
      const int q = qrow0 + l16;
      uint16_t* yp = Y + ((size_t)(b * T_ + q)) * C_ + h * HD_ + kg * 4;
#pragma unroll
      for (int njd = 0; njd < 4; ++njd) {
        f32x4 oc = o[njd] + cO[(njd * 4 + qw) * 64 + lane];
        uint2 w;
        w.x = cvtpk(oc[0] * inv, oc[1] * inv);
        w.y = cvtpk(oc[2] * inv, oc[3] * inv);
        *(uint2*)(yp + njd * 16) = w;
      }
    }
  }
}

extern "C" void kernel_launch(void* const* d_in, const int* in_sizes, int n_in,
                              void* d_out, int out_size, void* d_ws, size_t ws_size,
                              hipStream_t stream) {
  const float* x      = (const float*)d_in[0];
  const float* W_attn = (const float*)d_in[1];
  const float* b_attn = (const float*)d_in[2];
  const float* W_proj = (const float*)d_in[3];
  const float* b_proj = (const float*)d_in[4];
  float* out = (float*)d_out;

  char* ws = (char*)d_ws;
  uint16_t* xb  = (uint16_t*)(ws);
  uint16_t* WtA = (uint16_t*)(ws + 12582912);
  uint16_t* WtP = (uint16_t*)(ws + 16121856);
  uint16_t* QKV = (uint16_t*)(ws + 17301504);
  uint16_t* Yb  = (uint16_t*)(ws + 55050240);

  uint16_t* Qp = QKV;                // pre-scaled by QSCL
  uint16_t* Kp = QKV + 6291456;
  uint16_t* Vp = QKV + 12582912;     // [B,H,64,T]

  k_cvt<<<6144, 256, 0, stream>>>(x, xb, 1572864);
  k_tr2<<<dim3(96, 24), dim3(32, 8), 0, stream>>>(W_attn, WtA, W_proj, WtP);
  k_gemm<1><<<1152, 256, 0, stream>>>(xb, WtA, b_attn, nullptr, QKV, 8192, 2304, 768, 18);
  k_attn2<<<768, 512, 0, stream>>>(Qp, Kp, Vp, Yb);
  k_gemm<0><<<384, 256, 0, stream>>>(Yb, WtP, b_proj, out, nullptr, 8192, 768, 768, 6);
}

// Round 24
// 128.666 us; speedup vs baseline: 1.0888x; 1.0133x over previous
//
#include <hip/hip_runtime.h>
#include <hip/hip_bf16.h>
#include <cstdint>

#define B_  4
#define T_  2048
#define C_  768
#define H_  12
#define HD_ 64

#define AS1 __attribute__((address_space(1)))
#define AS3 __attribute__((address_space(3)))

typedef float    f32x4  __attribute__((ext_vector_type(4)));
typedef __bf16   bf16x8 __attribute__((ext_vector_type(8)));
typedef uint32_t u32x4  __attribute__((ext_vector_type(4)));

// log2(e)/8: folded into Q at GEMM1 epilogue -> softmax runs in exp2 domain.
#define QSCL 0.18033688011112042f

__device__ __forceinline__ uint16_t f2b(float f) {   // native RNE cvt
  __bf16 h = (__bf16)f;
  return __builtin_bit_cast(uint16_t, h);
}
__device__ __forceinline__ uint32_t pk2(float a, float b) {
  return (uint32_t)f2b(a) | ((uint32_t)f2b(b) << 16);
}
__device__ __forceinline__ uint32_t cvtpk(float lo, float hi) {  // HW packed cvt
  uint32_t r;
  asm("v_cvt_pk_bf16_f32 %0, %1, %2" : "=v"(r) : "v"(lo), "v"(hi));
  return r;
}

// ---- fused pre-pass: x->bf16 cast (blocks 0..6143) + both weight
// transposes (blocks 6144..8447). One launch; streams overlap. ----
__global__ void k_prep(const float* __restrict__ x, uint16_t* __restrict__ xb,
                       const float* __restrict__ Wa, uint16_t* __restrict__ WtA,
                       const float* __restrict__ Wp, uint16_t* __restrict__ WtP) {
  __shared__ float tile[32][33];
  const int bid = blockIdx.x;
  const int tid = threadIdx.x;
  if (bid < 6144) {
    int i = bid * 256 + tid;          // 6144*256 == 1572864 float4s exactly
    float4 v = ((const float4*)x)[i];
    uint2 o;
    o.x = pk2(v.x, v.y);
    o.y = pk2(v.z, v.w);
    ((uint2*)xb)[i] = o;
  } else {
    const int rb = bid - 6144;        // 0..2303
    const int bx = rb % 96;
    const int k0 = (rb / 96) * 32;    // 0..736
    const float* in;
    uint16_t* out;
    int Cc, n0;
    if (bx < 72) { in = Wa; out = WtA; Cc = 2304; n0 = bx * 32; }
    else         { in = Wp; out = WtP; Cc = 768;  n0 = (bx - 72) * 32; }
    const int tx = tid & 31, ty = tid >> 5;   // (32,8)
#pragma unroll
    for (int i = 0; i < 32; i += 8)
      tile[ty + i][tx] = in[(size_t)(k0 + ty + i) * Cc + n0 + tx];
    __syncthreads();
#pragma unroll
    for (int i = 0; i < 32; i += 8)
      out[(size_t)(n0 + ty + i) * 768 + k0 + tx] = f2b(tile[tx][ty + i]);
  }
}

// ---------------- MFMA bf16 GEMM (r13 exact — 55 us measured; dist-2,
// 3 buffers, vmcnt(4) steady-state; 1 barrier per k-step) ----------------
template <int EPI>
__global__ __launch_bounds__(256, 3) void k_gemm(
    const uint16_t* __restrict__ A, const uint16_t* __restrict__ Bt,
    const float* __restrict__ bias, float* __restrict__ outF,
    uint16_t* __restrict__ outQKV, int M, int N, int K, int nY) {
  __shared__ __align__(16) uint16_t As[3][128 * 32];
  __shared__ __align__(16) uint16_t Bs[3][128 * 32];
  const int nwg = gridDim.x;
  const int bid = blockIdx.x;
  const int wgid = (bid & 7) * (nwg >> 3) + (bid >> 3);
  const int wy = wgid % nY, wx = wgid / nY;

  const int tid  = threadIdx.x;
  const int lane = tid & 63;
  const int wave = tid >> 6;
  const int wrow = (wave >> 1) * 64, wcol = (wave & 1) * 64;
  const int rowBase = wx * 128, colBase = wy * 128;
  const int l16 = lane & 15, kg = lane >> 4;

  f32x4 acc[4][4];
#pragma unroll
  for (int i = 0; i < 4; ++i)
#pragma unroll
    for (int j = 0; j < 4; ++j) acc[i][j] = (f32x4){0.f, 0.f, 0.f, 0.f};

  const int srow  = lane >> 2;
  const int sslot = lane & 3;
  const int ssw   = (sslot ^ (srow & 3)) << 3;

  auto STAGE = [&](int buf, int k0) {
#pragma unroll
    for (int i = 0; i < 2; ++i) {
      const int r = i * 64 + wave * 16 + srow;
      const uint16_t* srcA = A  + (size_t)(rowBase + r) * K + k0 + ssw;
      const uint16_t* srcB = Bt + (size_t)(colBase + r) * K + k0 + ssw;
      uint16_t* dstA = &As[buf][(i * 64 + wave * 16) * 32];
      uint16_t* dstB = &Bs[buf][(i * 64 + wave * 16) * 32];
      __builtin_amdgcn_global_load_lds((const AS1 uint32_t*)srcA, (AS3 uint32_t*)dstA, 16, 0, 0);
      __builtin_amdgcn_global_load_lds((const AS1 uint32_t*)srcB, (AS3 uint32_t*)dstB, 16, 0, 0);
    }
  };

  const int sA = (kg ^ (l16 & 3)) << 3;

  STAGE(0, 0);
  if (32 < K) STAGE(1, 32);
  int t = 0;
  for (int k0 = 0; k0 < K; k0 += 32, ++t) {
    if (k0 + 32 < K) {
      asm volatile("s_waitcnt vmcnt(4)" ::: "memory");
    } else {
      asm volatile("s_waitcnt vmcnt(0)" ::: "memory");
    }
    __builtin_amdgcn_sched_barrier(0);
    __builtin_amdgcn_s_barrier();

    if (k0 + 64 < K) STAGE((t + 2) % 3, k0 + 64);

    const int cb = t % 3;
    bf16x8 af[4], bfv[4];
#pragma unroll
    for (int mi = 0; mi < 4; ++mi)
      af[mi] = *(const bf16x8*)&As[cb][(wrow + mi * 16 + l16) * 32 + sA];
#pragma unroll
    for (int nj = 0; nj < 4; ++nj)
      bfv[nj] = *(const bf16x8*)&Bs[cb][(wcol + nj * 16 + l16) * 32 + sA];
#pragma unroll
    for (int mi = 0; mi < 4; ++mi)
#pragma unroll
      for (int nj = 0; nj < 4; ++nj)
        acc[mi][nj] = __builtin_amdgcn_mfma_f32_16x16x32_bf16(af[mi], bfv[nj], acc[mi][nj], 0, 0, 0);
  }

  const int rg = lane >> 4;
#pragma unroll
  for (int mi = 0; mi < 4; ++mi)
#pragma unroll
    for (int nj = 0; nj < 4; ++nj) {
      int c = colBase + wcol + nj * 16 + l16;
      float bv = bias[c];
      if (EPI == 0) {
#pragma unroll
        for (int jj = 0; jj < 4; ++jj) {
          int r = rowBase + wrow + mi * 16 + rg * 4 + jj;
          outF[(size_t)r * N + c] = acc[mi][nj][jj] + bv;
        }
      } else {
        int sel = c / 768;
        int rem = c - sel * 768;
        int head = rem >> 6, d = rem & 63;
        int r0 = rowBase + wrow + mi * 16 + rg * 4;
        int bb = r0 >> 11, tt0 = r0 & 2047;
        if (sel == 2) {
          size_t off = (((size_t)2 * (B_ * H_) + bb * H_ + head) * HD_ + d) * T_ + tt0;
          uint2 w;
          w.x = pk2(acc[mi][nj][0] + bv, acc[mi][nj][1] + bv);
          w.y = pk2(acc[mi][nj][2] + bv, acc[mi][nj][3] + bv);
          *(uint2*)&outQKV[off] = w;
        } else {
          float scl = (sel == 0) ? QSCL : 1.0f;
#pragma unroll
          for (int jj = 0; jj < 4; ++jj) {
            size_t off = (((size_t)sel * (B_ * H_) + bb * H_ + head) * T_ + tt0 + jj) * HD_ + d;
            outQKV[off] = f2b((acc[mi][nj][jj] + bv) * scl);
          }
        }
      }
    }
}

// ---------------- MFMA flash attention, v11b (r19 exact — best measured) ----------------
__global__ __launch_bounds__(512, 6) void k_attn2(
    const uint16_t* __restrict__ Qb, const uint16_t* __restrict__ Kb,
    const uint16_t* __restrict__ Vb, uint16_t* __restrict__ Y) {
  __shared__ __align__(16) uint16_t Ks[2][64 * 64];
  __shared__ __align__(16) uint16_t Vs[2][64 * 64];
  __shared__ __align__(16) uint32_t Pw[8][16 * 20];   // per-wave P: 16 q x 32 kv
  const int tid  = threadIdx.x;
  const int lane = tid & 63;
  const int wq   = tid >> 6;           // wave 0..7
  const int qw   = wq & 3;             // q sub-block
  const int kh   = wq >> 2;            // kv half
  const int l16  = lane & 15, kg = lane >> 4;

  const int idx = blockIdx.x;
  const int tq  = idx >> 3;
  const int px  = tq & 15;
  const int g   = (idx & 7) + 8 * (tq >> 4);
  const int h = g % H_, b = g / H_;
  const size_t headBase = ((size_t)(b * H_ + h)) * (size_t)(T_ * HD_);

  const int srow0 = tid >> 3;          // 0..63
  const int sslot = lane & 7;
  const int ssw   = ((sslot ^ (srow0 & 7)) << 3);

  uint32_t* pw = &Pw[wq][0];
  uint16_t* dstK0 = &Ks[0][(wq * 8) * 64];
  uint16_t* dstK1 = &Ks[1][(wq * 8) * 64];
  uint16_t* dstV0 = &Vs[0][(wq * 8) * 64];
  uint16_t* dstV1 = &Vs[1][(wq * 8) * 64];

  // constant ones A-fragment for the l-summing MFMA
  u32x4 onesw;
  onesw[0] = 0x3f803f80u; onesw[1] = 0x3f803f80u;
  onesw[2] = 0x3f803f80u; onesw[3] = 0x3f803f80u;
  const bf16x8 onesf = __builtin_bit_cast(bf16x8, onesw);

  int cur = 0;
  for (int part = 0; part < 2; ++part) {
    const int qb = part ? (31 - px) : px;
    const int qrow0 = qb * 64 + qw * 16;

    bf16x8 qf[2];
    {
      const uint16_t* qp = Qb + headBase + (size_t)(qrow0 + l16) * HD_;
      qf[0] = *(const bf16x8*)(qp + kg * 8);
      qf[1] = *(const bf16x8*)(qp + 32 + kg * 8);
    }

    f32x4 o[4];
#pragma unroll
    for (int i = 0; i < 4; ++i) o[i] = (f32x4){0.f, 0.f, 0.f, 0.f};
    f32x4 lq = (f32x4){0.f, 0.f, 0.f, 0.f};   // l accumulator (ones-MFMA)

    // strength-reduced staging pointers (advance per STAGE call)
    const uint16_t* kp = Kb + headBase + (size_t)srow0 * HD_ + ssw;
    const uint16_t* vp = Vb + headBase + (size_t)srow0 * T_ + ssw;

    auto STAGE = [&](int buf) {          // 2 global_load_lds per thread
      __builtin_amdgcn_global_load_lds((const AS1 uint32_t*)kp,
                                       (AS3 uint32_t*)(buf ? dstK1 : dstK0), 16, 0, 0);
      __builtin_amdgcn_global_load_lds((const AS1 uint32_t*)vp,
                                       (AS3 uint32_t*)(buf ? dstV1 : dstV0), 16, 0, 0);
      kp += 64 * HD_;                    // next kv tile: +64 rows
      vp += 64;                          // next kv tile: +64 cols
    };

    const int nt = qb + 1;
    __syncthreads();          // part boundary: prior combine reads done
    STAGE(cur);

    for (int t = 0; t < nt; ++t) {
      asm volatile("s_waitcnt vmcnt(0)" ::: "memory");  // tile t landed (issued 1 phase ago)
      __builtin_amdgcn_sched_barrier(0);
      __builtin_amdgcn_s_barrier();      // all waves: t ready, compute(t-1) done

      if (t + 1 < nt) STAGE(cur ^ 1);    // overwrite safe: everyone passed barrier

      const uint16_t* KT = &Ks[cur][0];
      const uint16_t* VT = &Vs[cur][0];

      // --- S^T half: sm[nj][jj] = S[kv = kh*32+nj*16+kg*4+jj][q = l16] ---
      f32x4 sm[2];
      __builtin_amdgcn_s_setprio(1);
#pragma unroll
      for (int nj = 0; nj < 2; ++nj) {
        f32x4 acc = (f32x4){0.f, 0.f, 0.f, 0.f};
        const int row = kh * 32 + nj * 16 + l16;
#pragma unroll
        for (int kc = 0; kc < 2; ++kc) {
          const int s = (((kc * 4 + kg) ^ (row & 7)) << 3);
          bf16x8 kf = *(const bf16x8*)&KT[row * 64 + s];
          acc = __builtin_amdgcn_mfma_f32_16x16x32_bf16(kf, qf[kc], acc, 0, 0, 0);
        }
        sm[nj] = acc;
      }
      __builtin_amdgcn_s_setprio(0);

      if (t == qb) {  // diagonal tile: causal mask
        const int kvb = t * 64 + kh * 32 + kg * 4;
        const int qg  = qrow0 + l16;
#pragma unroll
        for (int nj = 0; nj < 2; ++nj)
#pragma unroll
          for (int jj = 0; jj < 4; ++jj)
            if (kvb + nj * 16 + jj > qg) sm[nj][jj] = -__builtin_inff();
      }

      // --- softmax numerator: p = exp2(S) (scale cancels in O/l) ---
#pragma unroll
      for (int nj = 0; nj < 2; ++nj)
#pragma unroll
        for (int jj = 0; jj < 4; ++jj)
          sm[nj][jj] = __builtin_exp2f(sm[nj][jj]);

      // --- P -> private LDS (row q=l16, 32 kv, stride 20 words); HW cvt_pk ---
#pragma unroll
      for (int nj = 0; nj < 2; ++nj) {
        uint2 w;
        w.x = cvtpk(sm[nj][0], sm[nj][1]);
        w.y = cvtpk(sm[nj][2], sm[nj][3]);
        *(uint2*)&pw[l16 * 20 + nj * 8 + kg * 2] = w;
      }

      // --- O^T(partial) += V^T[:, my half] P ; l via ones-MFMA ---
      __builtin_amdgcn_s_setprio(1);
      bf16x8 pa = *(const bf16x8*)&pw[l16 * 20 + kg * 4];
#pragma unroll
      for (int njd = 0; njd < 4; ++njd) {
        const int row = njd * 16 + l16;
        const int s = (((kh * 4 + kg) ^ (row & 7)) << 3);
        bf16x8 vf = *(const bf16x8*)&VT[row * 64 + s];
        o[njd] = __builtin_amdgcn_mfma_f32_16x16x32_bf16(vf, pa, o[njd], 0, 0, 0);
      }
      lq = __builtin_amdgcn_mfma_f32_16x16x32_bf16(onesf, pa, lq, 0, 0, 0);
      __builtin_amdgcn_s_setprio(0);

      cur ^= 1;
    }

    // --- combine kv-half partials via freed K/V LDS, then store ---
    float l_ = lq[0];                    // every lane holds l(q=l16) already

    __syncthreads();                     // all visits' LDS reads done
    f32x4* cO = (f32x4*)&Ks[0][0];
    float*  cL = (float*)&Vs[0][0];
    if (kh) {
#pragma unroll
      for (int njd = 0; njd < 4; ++njd) cO[(njd * 4 + qw) * 64 + lane] = o[njd];
      if (lane < 16) cL[qw * 64 + lane] = l_;
    }
    __syncthreads();
    if (!kh) {
      float lsum = l_ + cL[qw * 64 + l16];
      float inv = __builtin_amdgcn_rcpf(lsum);
      const int q = qrow0 + l16;
      uint16_t* yp = Y + ((size_t)(b * T_ + q)) * C_ + h * HD_ + kg * 4;
#pragma unroll
      for (int njd = 0; njd < 4; ++njd) {
        f32x4 oc = o[njd] + cO[(njd * 4 + qw) * 64 + lane];
        uint2 w;
        w.x = cvtpk(oc[0] * inv, oc[1] * inv);
        w.y = cvtpk(oc[2] * inv, oc[3] * inv);
        *(uint2*)(yp + njd * 16) = w;
      }
    }
  }
}

extern "C" void kernel_launch(void* const* d_in, const int* in_sizes, int n_in,
                              void* d_out, int out_size, void* d_ws, size_t ws_size,
                              hipStream_t stream) {
  const float* x      = (const float*)d_in[0];
  const float* W_attn = (const float*)d_in[1];
  const float* b_attn = (const float*)d_in[2];
  const float* W_proj = (const float*)d_in[3];
  const float* b_proj = (const float*)d_in[4];
  float* out = (float*)d_out;

  char* ws = (char*)d_ws;
  uint16_t* xb  = (uint16_t*)(ws);
  uint16_t* WtA = (uint16_t*)(ws + 12582912);
  uint16_t* WtP = (uint16_t*)(ws + 16121856);
  uint16_t* QKV = (uint16_t*)(ws + 17301504);
  uint16_t* Yb  = (uint16_t*)(ws + 55050240);

  uint16_t* Qp = QKV;                // pre-scaled by QSCL
  uint16_t* Kp = QKV + 6291456;
  uint16_t* Vp = QKV + 12582912;     // [B,H,64,T]

  k_prep<<<8448, 256, 0, stream>>>(x, xb, W_attn, WtA, W_proj, WtP);
  k_gemm<1><<<1152, 256, 0, stream>>>(xb, WtA, b_attn, nullptr, QKV, 8192, 2304, 768, 18);
  k_attn2<<<768, 512, 0, stream>>>(Qp, Kp, Vp, Yb);
  k_gemm<0><<<384, 256, 0, stream>>>(Yb, WtP, b_proj, out, nullptr, 8192, 768, 768, 6);
}